// Round 2
// baseline (155.513 us; speedup 1.0000x reference)
//
#include <hip/hip_runtime.h>
#include <math.h>

#define VOCAB   32000
#define BLTOT   128    // B*L
#define HTOT    64     // H = 8 heads * 8 hph
#define BLT     16     // bl rows accumulated per thread
#define VPB     256    // vocab rows per block (= threads per block)

#define LOG2E   1.44269504088896340736f

// ---------------------------------------------------------------------------
// Prep: build interleaved uniform table in ws (96 KB):
//   per (bl, jj):  [ef4 | emf4 | cw4]   (12 floats, 48 B)
//   ef  = 2^(f*log2e)  = e^f
//   emf = 2^(-f*log2e) = e^-f
//   cw  = amps * cos(phases - ip[j]) * W[j/8]
// Block-uniform addresses in the main kernel -> scalar loads (free pipe).
// ---------------------------------------------------------------------------
__global__ void prep_kernel(const float* __restrict__ freqs,
                            const float* __restrict__ amps,
                            const float* __restrict__ phases,
                            const float* __restrict__ ip,
                            const float* __restrict__ W,
                            float* __restrict__ ws) {
    int t = blockIdx.x * blockDim.x + threadIdx.x;   // 0 .. 8191
    if (t >= BLTOT * HTOT) return;
    int bl = t >> 6;
    int j  = t & 63;
    float fe = freqs[t] * LOG2E;
    float cw = amps[t] * cosf(phases[t] - ip[j]) * W[j >> 3];
    int jj = j >> 2, u = j & 3;
    float* base = ws + bl * 192 + jj * 12;
    base[u]     = __builtin_amdgcn_exp2f(fe);    // e^f
    base[4 + u] = __builtin_amdgcn_exp2f(-fe);   // e^-f
    base[8 + u] = cw;
}

// ---------------------------------------------------------------------------
// Main: thread owns one vocab row v, accumulates BLT=16 (b,l) outputs in
// registers. exp(-|f-v|) = min(e^f * e^-v, e^-f * e^v): the bl-side exps are
// precomputed scalars, the v-side exps computed once per jj and reused 16x.
// Inner body per element: v_mul, v_mul, v_min, v_fmac -- all full-rate.
// ---------------------------------------------------------------------------
__global__ __launch_bounds__(VPB) void
wave_main(const float* __restrict__ vp,     // vocab_patterns, VOCAB x 64
          const float* __restrict__ uni,    // ws table
          const float* __restrict__ bptr,   // bias (1 elem)
          float* __restrict__ out) {        // (B*L, VOCAB)
    const int v   = blockIdx.x * VPB + threadIdx.x;   // 32000 = 125*256 exact
    const int bl0 = blockIdx.y * BLT;                 // 128 = 8*16 exact

    const float4* __restrict__ vp4 = (const float4*)vp;
    const float4* __restrict__ u4  = (const float4*)uni;

    float acc[BLT];
#pragma unroll
    for (int i = 0; i < BLT; ++i) acc[i] = 0.0f;

#pragma unroll 4
    for (int jj = 0; jj < 16; ++jj) {
        const float4 vf = vp4[v * 16 + jj];           // per-thread vector load
        // v-side exponentials, once per jj (amortized over 16 bl rows)
        float4 sv; sv.x = vf.x * LOG2E; sv.y = vf.y * LOG2E;
                   sv.z = vf.z * LOG2E; sv.w = vf.w * LOG2E;
        float4 ev, emv;
        ev.x  = __builtin_amdgcn_exp2f( sv.x);  emv.x = __builtin_amdgcn_exp2f(-sv.x);
        ev.y  = __builtin_amdgcn_exp2f( sv.y);  emv.y = __builtin_amdgcn_exp2f(-sv.y);
        ev.z  = __builtin_amdgcn_exp2f( sv.z);  emv.z = __builtin_amdgcn_exp2f(-sv.z);
        ev.w  = __builtin_amdgcn_exp2f( sv.w);  emv.w = __builtin_amdgcn_exp2f(-sv.w);
#pragma unroll
        for (int i = 0; i < BLT; ++i) {
            // block-uniform addresses -> s_load_dwordx4 x3 (scalar pipe)
            const int base = ((bl0 + i) * 16 + jj) * 3;
            const float4 ef4  = u4[base];
            const float4 emf4 = u4[base + 1];
            const float4 cw4  = u4[base + 2];
            acc[i] = fmaf(cw4.x, fminf(ef4.x * emv.x, emf4.x * ev.x), acc[i]);
            acc[i] = fmaf(cw4.y, fminf(ef4.y * emv.y, emf4.y * ev.y), acc[i]);
            acc[i] = fmaf(cw4.z, fminf(ef4.z * emv.z, emf4.z * ev.z), acc[i]);
            acc[i] = fmaf(cw4.w, fminf(ef4.w * emv.w, emf4.w * ev.w), acc[i]);
        }
    }

    const float b0 = bptr[0];
#pragma unroll
    for (int i = 0; i < BLT; ++i)
        out[(bl0 + i) * VOCAB + v] = acc[i] + b0;     // coalesced stores
}

extern "C" void kernel_launch(void* const* d_in, const int* in_sizes, int n_in,
                              void* d_out, int out_size, void* d_ws, size_t ws_size,
                              hipStream_t stream) {
    const float* freqs  = (const float*)d_in[0];
    const float* amps   = (const float*)d_in[1];
    const float* phases = (const float*)d_in[2];
    const float* vp     = (const float*)d_in[3];
    const float* ip     = (const float*)d_in[4];
    const float* W      = (const float*)d_in[5];
    const float* b      = (const float*)d_in[6];
    float* out = (float*)d_out;
    float* ws  = (float*)d_ws;   // needs 96 KB

    // 1) build uniform {e^f, e^-f, cw} table
    prep_kernel<<<dim3(32), dim3(256), 0, stream>>>(freqs, amps, phases, ip, W, ws);

    // 2) main interference kernel: 125 vocab tiles x 8 bl-groups
    wave_main<<<dim3(VOCAB / VPB, BLTOT / BLT), dim3(VPB), 0, stream>>>(vp, ws, b, out);
}

// Round 3
// 122.484 us; speedup vs baseline: 1.2697x; 1.2697x over previous
//
#include <hip/hip_runtime.h>
#include <math.h>

#define VOCAB   32000
#define BLTOT   128    // B*L
#define HTOT    64     // H = 8 heads * 8 hph
#define BLT     8      // bl rows accumulated per thread
#define VPB     256    // vocab rows per block (= threads per block)

#define LOG2E   1.44269504088896340736f

typedef float v2f __attribute__((ext_vector_type(2)));

// packed fp32 helpers (VOP3P, gfx90a+): 2 lanes of work per issue slot
static __device__ __forceinline__ v2f pk_add(v2f a, v2f b) {
    v2f d;
    asm("v_pk_add_f32 %0, %1, %2" : "=v"(d) : "v"(a), "v"(b));
    return d;
}
static __device__ __forceinline__ v2f pk_fma(v2f a, v2f b, v2f c) {
    asm("v_pk_fma_f32 %0, %1, %2, %0" : "+v"(c) : "v"(a), "v"(b));
    return c;
}

// ---------------------------------------------------------------------------
// Prep: 64 KB table in ws, per (bl, jj): [negfe4 | cw4]
//   negfe = -f * log2e      (so main kernel does pk_add, no neg modifier)
//   cw    = amps * cos(phases - ip[j]) * W[j/8]
// ---------------------------------------------------------------------------
__global__ void prep_kernel(const float* __restrict__ freqs,
                            const float* __restrict__ amps,
                            const float* __restrict__ phases,
                            const float* __restrict__ ip,
                            const float* __restrict__ W,
                            float* __restrict__ ws) {
    int t = blockIdx.x * blockDim.x + threadIdx.x;   // 0 .. 8191
    if (t >= BLTOT * HTOT) return;
    int bl = t >> 6;
    int j  = t & 63;
    float negfe = -freqs[t] * LOG2E;
    float cw = amps[t] * cosf(phases[t] - ip[j]) * W[j >> 3];
    int jj = j >> 2, u = j & 3;
    float* base = ws + bl * 128 + jj * 8;
    base[u]     = negfe;
    base[4 + u] = cw;
}

// ---------------------------------------------------------------------------
// Main: thread owns one vocab row v, accumulates BLT=8 (b,l) outputs in
// packed float2 accumulator pairs.  exp(-|f-v|) = exp2(-|v*log2e + negfe|).
// Per 4-element unit: 2 ds_read_b128 (broadcast) + 2 pk_add + 4 v_exp +
// 2 pk_fma = 8 VALU issue slots (was 12-16 in R1/R2).
// Table slice (4 KB) staged into LDS once; broadcast ds_reads are in-order
// and conflict-free, unlike the SMEM s_load drain stalls of R1/R2.
// ---------------------------------------------------------------------------
__global__ __launch_bounds__(VPB, 6) void
wave_main(const float* __restrict__ vp,     // vocab_patterns, VOCAB x 64
          const float* __restrict__ uni,    // ws table
          const float* __restrict__ bptr,   // bias (1 elem)
          float* __restrict__ out) {        // (B*L, VOCAB)
    const int v   = blockIdx.x * VPB + threadIdx.x;   // 32000 = 125*256 exact
    const int bl0 = blockIdx.y * BLT;                 // 128 = 16*8 exact

    __shared__ float4 smem[BLT * 16 * 2];             // 4 KB: [negfe4|cw4] per (bl,jj)

    // stage this block's table slice: 256 float4 = 4 KB, fully coalesced
    smem[threadIdx.x] = ((const float4*)(uni + bl0 * 128))[threadIdx.x];
    __syncthreads();

    const float4* __restrict__ vp4 = (const float4*)vp;

    v2f acc01[BLT], acc23[BLT];
#pragma unroll
    for (int i = 0; i < BLT; ++i) { acc01[i] = (v2f)(0.0f); acc23[i] = (v2f)(0.0f); }

#pragma unroll 2
    for (int jj = 0; jj < 16; ++jj) {
        const float4 vf = vp4[v * 16 + jj];           // per-thread vector load
        v2f ve01, ve23;
        ve01.x = vf.x * LOG2E; ve01.y = vf.y * LOG2E;
        ve23.x = vf.z * LOG2E; ve23.y = vf.w * LOG2E;
#pragma unroll
        for (int i = 0; i < BLT; ++i) {
            const float4 f4 = smem[(i * 16 + jj) * 2];       // negfe, broadcast
            const float4 c4 = smem[(i * 16 + jj) * 2 + 1];   // cw,    broadcast
            v2f d01 = pk_add(v2f{f4.x, f4.y}, ve01);
            v2f d23 = pk_add(v2f{f4.z, f4.w}, ve23);
            v2f e01, e23;
            e01.x = __builtin_amdgcn_exp2f(-__builtin_fabsf(d01.x));
            e01.y = __builtin_amdgcn_exp2f(-__builtin_fabsf(d01.y));
            e23.x = __builtin_amdgcn_exp2f(-__builtin_fabsf(d23.x));
            e23.y = __builtin_amdgcn_exp2f(-__builtin_fabsf(d23.y));
            acc01[i] = pk_fma(v2f{c4.x, c4.y}, e01, acc01[i]);
            acc23[i] = pk_fma(v2f{c4.z, c4.w}, e23, acc23[i]);
        }
    }

    const float b0 = bptr[0];
#pragma unroll
    for (int i = 0; i < BLT; ++i) {
        float s = (acc01[i].x + acc01[i].y) + (acc23[i].x + acc23[i].y);
        out[(bl0 + i) * VOCAB + v] = s + b0;          // coalesced stores
    }
}

extern "C" void kernel_launch(void* const* d_in, const int* in_sizes, int n_in,
                              void* d_out, int out_size, void* d_ws, size_t ws_size,
                              hipStream_t stream) {
    const float* freqs  = (const float*)d_in[0];
    const float* amps   = (const float*)d_in[1];
    const float* phases = (const float*)d_in[2];
    const float* vp     = (const float*)d_in[3];
    const float* ip     = (const float*)d_in[4];
    const float* W      = (const float*)d_in[5];
    const float* b      = (const float*)d_in[6];
    float* out = (float*)d_out;
    float* ws  = (float*)d_ws;   // needs 64 KB

    // 1) build uniform {-f*log2e, cw} table
    prep_kernel<<<dim3(32), dim3(256), 0, stream>>>(freqs, amps, phases, ip, W, ws);

    // 2) main interference kernel: 125 vocab tiles x 16 bl-groups (2000 blocks)
    wave_main<<<dim3(VOCAB / VPB, BLTOT / BLT), dim3(VPB), 0, stream>>>(vp, ws, b, out);
}